// Round 1
// 152.461 us; speedup vs baseline: 1.0284x; 1.0284x over previous
//
#include <hip/hip_runtime.h>

// Problem constants
#define N_ROWS 131072    // 32*4096
#define D 64
#define K_CODES 1024

typedef _Float16 f16x8 __attribute__((ext_vector_type(8)));
typedef float    f32x4 __attribute__((ext_vector_type(4)));

#define MFMA16(a, b, c) __builtin_amdgcn_mfma_f32_16x16x32_f16((a), (b), (c), 0, 0, 0)

// ---------------------------------------------------------------------------
// ws layout: csqr[1024] f32 (4 KB) | CBf: 16384 f16x8 units (256 KB)
// CBf unit index = tile*256 + f*64 + lane, f in {0:hi k0-31, 1:hi k32-63,
// 2:lo k0-31, 3:lo k32-63}; unit holds the 8 halves lane needs for that
// MFMA B fragment: B[k=(lane>>4)*8+j][n=lane&15], code = tile*16 + n.
// (UNCHANGED from previous version.)
// ---------------------------------------------------------------------------
__global__ __launch_bounds__(256)
void prep_kernel(const float* __restrict__ CB, _Float16* __restrict__ CBf,
                 float* __restrict__ csqr, float* __restrict__ loss) {
    const int b = blockIdx.x, t = threadIdx.x;
    if (b < 64) {
        const int unit = b * 256 + t;
        const int tile = unit >> 8;
        const int f    = (unit >> 6) & 3;
        const int lane = unit & 63;
        const int quad = lane >> 4, lrow = lane & 15;
        const int code = tile * 16 + lrow;
        const int k0   = (f & 1) * 32 + quad * 8;
        const float* src = CB + (size_t)code * D + k0;
        float4 v0 = *(const float4*)(src);
        float4 v1 = *(const float4*)(src + 4);
        float xs[8] = {v0.x, v0.y, v0.z, v0.w, v1.x, v1.y, v1.z, v1.w};
        f16x8 o;
#pragma unroll
        for (int j = 0; j < 8; ++j) {
            _Float16 h = (_Float16)xs[j];
            o[j] = (f < 2) ? h : (_Float16)(xs[j] - (float)h);
        }
        *(f16x8*)(CBf + (size_t)unit * 8) = o;
    } else {
        if (t == 0) *loss = 0.0f;
        for (int k = t; k < K_CODES; k += 256) {
            const float4* p = (const float4*)(CB + (size_t)k * D);
            float s = 0.0f;
#pragma unroll
            for (int i = 0; i < 16; ++i) {
                float4 v = p[i];
                s += v.x * v.x + v.y * v.y + v.z * v.z + v.w * v.w;
            }
            csqr[k] = s;
        }
    }
}

// ---------------------------------------------------------------------------
// K1 (MT=4): split-f16 MFMA argmin + fused z_q + loss, ASM-PINNED prefetch.
// Block = 128 rows, 4 waves partitioned as (row-half, code-half):
//   wave w: rows [R0 + (w>>1)*64, +64) x codes [(w&1)*512, +512)  (32 tiles).
// CHANGE vs previous: MT 2 -> 4 (64 rows/wave). Per tile: 24 MFMAs against
// the SAME 4 B-loads -> per-wave MFMA issue density ~74% (was ~60%), 4
// independent 6-deep acc chains feed the matrix pipe from one wave, and
// B L2 traffic halves (1 GB -> 0.5 GB). Grid 2048 -> 1024 (2 clean
// residency rounds at 2 blocks/CU). VGPR ~190 under __launch_bounds__(256,2).
// vmcnt bookkeeping UNCHANGED: 4 loads/group, 3 younger groups outstanding
// before a buffer is consumed -> vmcnt(12) retires its group.
// score = |c|^2 + (-2x)·c, acc-init = csqr, 6 MFMAs/tile/mt (hh,lh,hl;
// ll ~2^-24 dropped). Cross-wave merge via LDS (code-half 0 has smaller
// indices -> '<' keeps np.argmin first-min). Epilogue: block-cooperative
// contiguous zq span write (16B-aligned despite out+1), now 8192 dwords.
// ---------------------------------------------------------------------------
__global__ __launch_bounds__(256, 2)
void argmin_kernel(const float* __restrict__ X,
                   const _Float16* __restrict__ CBf,
                   const float* __restrict__ csqr,
                   const float* __restrict__ CB,
                   float* __restrict__ out) {
    __shared__ float LsC[K_CODES];       // csqr copy, 4 KB
    __shared__ float candD[128][2];
    __shared__ int   candI[128][2];
    __shared__ int   ivfin[128];
    __shared__ float xsqW[2];
    __shared__ float lossW[2];

    const int t    = threadIdx.x;
    const int wave = t >> 6;
    const int lane = t & 63;
    const int lrow = lane & 15;
    const int quad = lane >> 4;
    const int rh   = wave >> 1;          // row half
    const int ch   = wave & 1;           // code half
    const int R0   = blockIdx.x * 128;
    const int Rw   = R0 + rh * 64;

    // Stage csqr to LDS (covered by the barrier below).
    ((float4*)LsC)[t] = ((const float4*)csqr)[t];

    // ---- A fragments: (-2x) split hi/lo; xsq accumulated (ch==0 waves
    // contribute so each block element is counted exactly once).
    // A layout: lane holds A[m=lane&15][k=quad*8+j], j=0..7.
    f16x8 Ah[4][2], Al[4][2];
    float xsq = 0.0f;
#pragma unroll
    for (int mt = 0; mt < 4; ++mt) {
        const float* xr = X + (size_t)(Rw + mt * 16 + lrow) * D;
#pragma unroll
        for (int ks = 0; ks < 2; ++ks) {
            const int k0 = ks * 32 + quad * 8;
            float4 v0 = *(const float4*)(xr + k0);
            float4 v1 = *(const float4*)(xr + k0 + 4);
            float xs[8] = {v0.x, v0.y, v0.z, v0.w, v1.x, v1.y, v1.z, v1.w};
            f16x8 h, l;
#pragma unroll
            for (int j = 0; j < 8; ++j) {
                xsq += xs[j] * xs[j];
                float sv = -2.0f * xs[j];
                _Float16 hh = (_Float16)sv;
                h[j] = hh;
                l[j] = (_Float16)(sv - (float)hh);
            }
            Ah[mt][ks] = h;
            Al[mt][ks] = l;
        }
    }
    __syncthreads();   // LsC ready (A-load vmcnt drained by compiler here)

    float bestd[4][4];
    int   besti[4][4];
#pragma unroll
    for (int mt = 0; mt < 4; ++mt)
#pragma unroll
        for (int r = 0; r < 4; ++r) { bestd[mt][r] = 3.0e38f; besti[mt][r] = 0; }

    // Wave's code range starts at tile ch*32.
    const f16x8* gw = (const f16x8*)CBf + (size_t)ch * 32 * 256 + lane;

// Inline-asm load group: 4x dwordx4, byte offsets 0/1024/2048/3072 from the
// per-tile base. Early-clobber outs so the addr pair is never overwritten.
#define ALOAD(Bv, tl)                                                         \
    do {                                                                      \
        const f16x8* _p = gw + (size_t)(tl) * 256;                            \
        asm volatile(                                                         \
            "global_load_dwordx4 %0, %4, off\n\t"                             \
            "global_load_dwordx4 %1, %4, off offset:1024\n\t"                 \
            "global_load_dwordx4 %2, %4, off offset:2048\n\t"                 \
            "global_load_dwordx4 %3, %4, off offset:3072"                     \
            : "=&v"(Bv[0]), "=&v"(Bv[1]), "=&v"(Bv[2]), "=&v"(Bv[3])          \
            : "v"(_p));                                                       \
    } while (0)

// Wait until this buffer's group retired (3 younger groups = 12 loads may
// remain). Data-tied (+v) so consuming MFMAs cannot float above the wait.
#define WAITB(Bv)                                                             \
    asm volatile("s_waitcnt vmcnt(12)"                                        \
                 : "+v"(Bv[0]), "+v"(Bv[1]), "+v"(Bv[2]), "+v"(Bv[3]))

#define COMPUTE(Bv, tl)                                                       \
    do {                                                                      \
        const int   c  = (ch * 32 + (tl)) * 16 + lrow;                        \
        const float cs = LsC[c];                                              \
        _Pragma("unroll")                                                     \
        for (int mt = 0; mt < 4; ++mt) {                                      \
            f32x4 acc = {cs, cs, cs, cs};                                     \
            acc = MFMA16(Ah[mt][0], Bv[0], acc);                              \
            acc = MFMA16(Ah[mt][1], Bv[1], acc);                              \
            acc = MFMA16(Al[mt][0], Bv[0], acc);                              \
            acc = MFMA16(Al[mt][1], Bv[1], acc);                              \
            acc = MFMA16(Ah[mt][0], Bv[2], acc);                              \
            acc = MFMA16(Ah[mt][1], Bv[3], acc);                              \
            _Pragma("unroll")                                                 \
            for (int r = 0; r < 4; ++r) {                                     \
                bool lt = acc[r] < bestd[mt][r];                              \
                bestd[mt][r] = lt ? acc[r] : bestd[mt][r];                    \
                besti[mt][r] = lt ? c : besti[mt][r];                         \
            }                                                                 \
        }                                                                     \
    } while (0)

    // 32 local tiles, 4-buffer asm pipeline, distance-3. Overrun loads wrap
    // via &31 (reloaded, never computed) so all stay inside CBf. Codes
    // ascend with tl for fixed lane -> strict < keeps np.argmin first-min.
    f16x8 B0[4], B1[4], B2[4], B3[4];
    ALOAD(B0, 0);
    ALOAD(B1, 1);
    ALOAD(B2, 2);
    for (int tl = 0; tl < 32; tl += 4) {
        ALOAD(B3, (tl + 3) & 31);
        WAITB(B0);
        COMPUTE(B0, tl);
        ALOAD(B0, (tl + 4) & 31);
        WAITB(B1);
        COMPUTE(B1, tl + 1);
        ALOAD(B1, (tl + 5) & 31);
        WAITB(B2);
        COMPUTE(B2, tl + 2);
        ALOAD(B2, (tl + 6) & 31);
        WAITB(B3);
        COMPUTE(B3, tl + 3);
    }
    // Drain all in-flight asm loads before their dest regs can be reused.
    asm volatile("s_waitcnt vmcnt(0)"
                 :
                 : "v"(B0[0]), "v"(B0[1]), "v"(B0[2]), "v"(B0[3]),
                   "v"(B1[0]), "v"(B1[1]), "v"(B1[2]), "v"(B1[3]),
                   "v"(B2[0]), "v"(B2[1]), "v"(B2[2]), "v"(B2[3]),
                   "v"(B3[0]), "v"(B3[1]), "v"(B3[2]), "v"(B3[3])
                 : "memory");

    // ---- xsq: reduce within ch==0 waves (each block element once).
    if (ch == 0) {
        float s = xsq;
#pragma unroll
        for (int m = 1; m < 64; m <<= 1) s += __shfl_xor(s, m, 64);
        if (lane == 0) xsqW[rh] = s;
    }

    // ---- In-wave argmin reduce across the 16 code-columns (lexicographic
    // on exact ties), deposit per-row candidate for this code half.
#pragma unroll
    for (int mt = 0; mt < 4; ++mt) {
#pragma unroll
        for (int r = 0; r < 4; ++r) {
            float dv = bestd[mt][r];
            int   iv = besti[mt][r];
#pragma unroll
            for (int m = 1; m < 16; m <<= 1) {
                float od = __shfl_xor(dv, m, 64);
                int   oi = __shfl_xor(iv, m, 64);
                if (od < dv || (od == dv && oi < iv)) { dv = od; iv = oi; }
            }
            if (lrow == 0) {
                int rl = rh * 64 + mt * 16 + quad * 4 + r;   // 0..127
                candD[rl][ch] = dv;
                candI[rl][ch] = iv;
            }
        }
    }
    __syncthreads();

    // ---- Merge the two code halves (2 waves handle 128 rows); write idxf;
    // accumulate per-wave loss partials.
    const float scale = 1.25f / (float)((size_t)N_ROWS * D);
    if (t < 128) {
        float d0 = candD[t][0], d1 = candD[t][1];
        int   i0 = candI[t][0], i1 = candI[t][1];
        // ch0 indices are all < ch1 indices -> tie keeps ch0 (first min).
        bool take1 = d1 < d0;
        float dv = take1 ? d1 : d0;
        int   iv = take1 ? i1 : i0;
        out[1 + (size_t)N_ROWS * D + R0 + t] = (float)iv;   // idxf
        ivfin[t] = iv;
        float ssum = dv;
#pragma unroll
        for (int m = 1; m < 64; m <<= 1) ssum += __shfl_xor(ssum, m, 64);
        if (lane == 0) lossW[wave] = ssum;   // wave 0 / wave 1 partial
    }
    __syncthreads();
    if (t == 0)
        atomicAdd(out, (lossW[0] + lossW[1] + xsqW[0] + xsqW[1]) * scale);

    // ---- Block-cooperative zq span write: dwords [R0*64, R0*64+8192) at
    // out+1. Global dword offset 1+R0*64+j is 16B-aligned iff j%4==3.
    float* p = out + 1 + (size_t)R0 * D;
#pragma unroll
    for (int i = 0; i < 8; ++i) {
        int q = i * 256 + t;        // 0..2047
        int j = 4 * q + 3;          // 3,7,...,8191
        if (q < 2047) {
            float v[4];
#pragma unroll
            for (int e = 0; e < 4; ++e) {
                int jj = j + e;     // may straddle a row boundary
                v[e] = CB[(size_t)ivfin[jj >> 6] * D + (jj & 63)];
            }
            *(float4*)(p + j) = make_float4(v[0], v[1], v[2], v[3]);
        } else if (q == 2047) {
            p[8191] = CB[(size_t)ivfin[127] * D + 63];
        }
    }
    if (t == 0) {   // head dwords j=0..2 (row 0, cols 0..2)
        const float* c0 = CB + (size_t)ivfin[0] * D;
        p[0] = c0[0];
        p[1] = c0[1];
        p[2] = c0[2];
    }
}

// ---------------------------------------------------------------------------
extern "C" void kernel_launch(void* const* d_in, const int* in_sizes, int n_in,
                              void* d_out, int out_size, void* d_ws,
                              size_t ws_size, hipStream_t stream) {
    const float* X  = (const float*)d_in[0];   // inputs  [131072,64]
    const float* CB = (const float*)d_in[1];   // codebook [1024,64]

    float*    csqr = (float*)d_ws;                      // 4 KB
    _Float16* CBf  = (_Float16*)((char*)d_ws + 4096);   // 256 KB

    hipLaunchKernelGGL(prep_kernel, dim3(65), dim3(256), 0, stream,
                       CB, CBf, csqr, (float*)d_out);
    hipLaunchKernelGGL(argmin_kernel, dim3(N_ROWS / 128), dim3(256), 0, stream,
                       X, CBf, csqr, CB, (float*)d_out);
}